// Round 2
// baseline (1878.585 us; speedup 1.0000x reference)
//
#include <hip/hip_runtime.h>
#include <hip/hip_bf16.h>

#define T_ 4
#define B_ 8
#define S_ 1024
#define D_ 768
#define BS_ (B_*S_)            // 8192
#define M_ (T_*B_*S_)          // 32768
#define BSD_ (B_*S_*D_)        // 6291456
#define LN_EPS 1e-5f

typedef unsigned short u16;
typedef unsigned char u8;
typedef unsigned long long u64;
typedef __bf16 bf16x8 __attribute__((ext_vector_type(8)));
typedef float f32x4 __attribute__((ext_vector_type(4)));

// ---- IF over x -> bitmask spikes, bit-exact vs np (sequential f32 adds) ----
// Am layout: [t][kw(12)][bs(8192)] u64; bit kb of word kw = spike at d=kw*64+kb
__global__ __launch_bounds__(768)
void k_if_mask(const float* __restrict__ x, u64* __restrict__ Am) {
    int bs = blockIdx.x;           // 8192 blocks
    int d = threadIdx.x;           // 768 threads
    int wv = d >> 6, lane = d & 63;
    float v = 0.f;
    for (int t = 0; t < T_; ++t) {
        v += x[(size_t)t * BSD_ + (size_t)bs * D_ + d];
        bool s = (v >= 1.0f);
        u64 m = __ballot(s);
        if (lane == 0) Am[((size_t)t * 12 + wv) * BS_ + bs] = m;
        if (s) v = 0.f;
    }
}

// ---- wo -> bf16 transposed [N][K] for MFMA ----
__global__ void k_wconv_o(const float* __restrict__ wo, u16* __restrict__ Wo) {
    int idx = blockIdx.x * 256 + threadIdx.x;  // 2304 blocks
    int n = idx / D_, k = idx % D_;
    __bf16 h = (__bf16)wo[k * D_ + n];
    Wo[idx] = __builtin_bit_cast(u16, h);
}

// ---- bitwise-np GEMM: Y[i,j] = sum over set bits k (ascending) of W[k,j],
// one f32 rounding per add == BLAS sgemm with A in {0,1}.
// Block: 192 threads = 3 waves (wave = 256 cols), 16 rows. Masks wave-uniform
// -> scalar branches; each set bit costs 4 v_add_f32.
__global__ __launch_bounds__(192)
void k_bitgemm(const u64* __restrict__ Am, const float* __restrict__ W,
               float* __restrict__ Y) {
    int rowbase = blockIdx.x * 16;             // 2048 blocks
    int t = rowbase >> 13;
    int bs0 = rowbase & (BS_ - 1);
    int tid = threadIdx.x;
    int j0 = (tid >> 6) * 256 + (tid & 63) * 4;
    float acc[16][4];
    #pragma unroll
    for (int r = 0; r < 16; ++r) {
        acc[r][0] = 0.f; acc[r][1] = 0.f; acc[r][2] = 0.f; acc[r][3] = 0.f;
    }
    for (int kw = 0; kw < 12; ++kw) {
        const u64* mp = Am + ((size_t)t * 12 + kw) * BS_ + bs0;
        u64 mk[16];
        #pragma unroll
        for (int r = 0; r < 16; ++r) mk[r] = mp[r];
        #pragma unroll 8
        for (int kb = 0; kb < 64; ++kb) {
            const float* wp = W + (size_t)(kw * 64 + kb) * D_ + j0;
            float4 w4 = *(const float4*)wp;
            #pragma unroll
            for (int r = 0; r < 16; ++r) {
                if (__builtin_expect((int)((mk[r] >> kb) & 1ull), 0)) {
                    acc[r][0] += w4.x; acc[r][1] += w4.y;
                    acc[r][2] += w4.z; acc[r][3] += w4.w;
                }
            }
        }
    }
    #pragma unroll
    for (int r = 0; r < 16; ++r) {
        float4 o;
        o.x = acc[r][0]; o.y = acc[r][1]; o.z = acc[r][2]; o.w = acc[r][3];
        *(float4*)(Y + (size_t)(rowbase + r) * D_ + j0) = o;
    }
}

// ---- LN (f64 mean/var; f32 final chain in np op order) + IF -> u8 spikes ----
__global__ __launch_bounds__(256)
void k_lnif(const float* __restrict__ Y, const float* __restrict__ g,
            const float* __restrict__ bt, u8* __restrict__ Sp) {
    #pragma clang fp contract(off)
    int row = blockIdx.x * 4 + (threadIdx.x >> 6);   // (b,s) 0..8191
    int lane = threadIdx.x & 63;
    float v[12];
    #pragma unroll
    for (int i = 0; i < 12; ++i) v[i] = 0.f;
    float gv[12], bv[12];
    #pragma unroll
    for (int i = 0; i < 12; ++i) { gv[i] = g[lane + 64*i]; bv[i] = bt[lane + 64*i]; }
    for (int t = 0; t < T_; ++t) {
        size_t base = ((size_t)t * BS_ + row) * D_;
        float xv[12];
        double s = 0.0;
        #pragma unroll
        for (int i = 0; i < 12; ++i) { xv[i] = Y[base + lane + 64*i]; s += (double)xv[i]; }
        #pragma unroll
        for (int o = 1; o < 64; o <<= 1) s += __shfl_xor(s, o, 64);
        s = __shfl(s, 0, 64);
        float m = (float)(s / 768.0);
        float d[12];
        double q = 0.0;
        #pragma unroll
        for (int i = 0; i < 12; ++i) { d[i] = xv[i] - m; float sq = d[i]*d[i]; q += (double)sq; }
        #pragma unroll
        for (int o = 1; o < 64; o <<= 1) q += __shfl_xor(q, o, 64);
        q = __shfl(q, 0, 64);
        float var = (float)(q / 768.0);
        float inv = 1.0f / __fsqrt_rn(var + LN_EPS);
        #pragma unroll
        for (int i = 0; i < 12; ++i) {
            float yn = ((d[i] * inv) * gv[i]) + bv[i];
            v[i] += yn;
            bool sp = (v[i] >= 1.0f);
            Sp[base + lane + 64*i] = sp ? (u8)1 : (u8)0;
            if (sp) v[i] = 0.f;
        }
    }
}

// ---- MFMA GEMM (post-spike only): C[M,N] = A[M,K] @ Bt[N,K]^T ----
__device__ __forceinline__ void gload16(const void* g, void* l) {
    __builtin_amdgcn_global_load_lds(
        (const __attribute__((address_space(1))) unsigned int*)g,
        (__attribute__((address_space(3))) unsigned int*)l, 16, 0, 0);
}

__global__ __launch_bounds__(256)
void k_gemm(const u16* __restrict__ A, const u16* __restrict__ Bt,
            float* __restrict__ C, int ntn, int N) {
    __shared__ __align__(16) u16 As[128 * 32];
    __shared__ __align__(16) u16 Bs[128 * 32];
    int bid = blockIdx.x;
    int bn = bid % ntn, bm = bid / ntn;
    int tid = threadIdx.x;
    int l = tid & 63, w = tid >> 6;
    int wr = w >> 1, wc = w & 1;
    int lan16 = l & 15, kh = l >> 4;

    f32x4 acc[4][4];
    #pragma unroll
    for (int m = 0; m < 4; ++m)
        #pragma unroll
        for (int n = 0; n < 4; ++n)
            #pragma unroll
            for (int r = 0; r < 4; ++r) acc[m][n][r] = 0.f;

    int arow = bm * 128 + (tid >> 2);
    int brow = bn * 128 + (tid >> 2);
    int colb = (tid & 3) * 8;
    char* ldsA = (char*)As + ((tid >> 6) << 10);
    char* ldsB = (char*)Bs + ((tid >> 6) << 10);

    for (int kk = 0; kk < 768; kk += 32) {
        gload16(A  + (size_t)(arow     ) * 768 + kk + colb, ldsA);
        gload16(A  + (size_t)(arow + 64) * 768 + kk + colb, ldsA + 4096);
        gload16(Bt + (size_t)(brow     ) * 768 + kk + colb, ldsB);
        gload16(Bt + (size_t)(brow + 64) * 768 + kk + colb, ldsB + 4096);
        __syncthreads();
        bf16x8 af[4], bf[4];
        #pragma unroll
        for (int m = 0; m < 4; ++m)
            af[m] = *(const bf16x8*)((const char*)As + (wr * 64 + m * 16 + lan16) * 64 + kh * 16);
        #pragma unroll
        for (int n = 0; n < 4; ++n)
            bf[n] = *(const bf16x8*)((const char*)Bs + (wc * 64 + n * 16 + lan16) * 64 + kh * 16);
        #pragma unroll
        for (int m = 0; m < 4; ++m)
            #pragma unroll
            for (int n = 0; n < 4; ++n)
                acc[m][n] = __builtin_amdgcn_mfma_f32_16x16x32_bf16(af[m], bf[n], acc[m][n], 0, 0, 0);
        __syncthreads();
    }
    #pragma unroll
    for (int m = 0; m < 4; ++m)
        #pragma unroll
        for (int n = 0; n < 4; ++n)
            #pragma unroll
            for (int r = 0; r < 4; ++r) {
                int crow = bm * 128 + wr * 64 + m * 16 + kh * 4 + r;
                int ccol = bn * 128 + wc * 64 + n * 16 + lan16;
                C[(size_t)crow * N + ccol] = acc[m][n][r];
            }
}

// ---- QK column-dot over S (exact integer counts) ----
__global__ void k_qkred(const u8* __restrict__ Q, const u8* __restrict__ K,
                        float* __restrict__ QK) {
    int bid = blockIdx.x;           // 256 blocks, 192 threads
    int sg = bid & 7, tb = bid >> 3;
    int tid = threadIdx.x;
    int c4 = tid * 4;
    size_t base = (size_t)tb * S_ * D_ + (size_t)sg * 128 * D_;
    int acc[4] = {0, 0, 0, 0};
    for (int s = 0; s < 128; ++s) {
        uchar4 q = *(const uchar4*)(Q + base + (size_t)s * D_ + c4);
        uchar4 k = *(const uchar4*)(K + base + (size_t)s * D_ + c4);
        acc[0] += q.x & k.x; acc[1] += q.y & k.y; acc[2] += q.z & k.z; acc[3] += q.w & k.w;
    }
    float* dst = QK + (size_t)tb * D_ + c4;
    #pragma unroll
    for (int j = 0; j < 4; ++j) atomicAdd(dst + j, (float)acc[j]);
}

// ---- IF over T on QK counts (integer-exact) ----
__global__ void k_qkif(const float* __restrict__ QK, u8* __restrict__ QKs) {
    int i = blockIdx.x * 256 + threadIdx.x;     // 24 blocks
    float v = 0.f;
    for (int t = 0; t < T_; ++t) {
        v += QK[t * (B_ * D_) + i];
        bool s = (v >= 1.0f);
        QKs[t * (B_ * D_) + i] = s ? 1 : 0;
        if (s) v = 0.f;
    }
}

// ---- QKV = V * QKs -> bf16 {0,1} ----
__global__ void k_qkv(const u8* __restrict__ V, const u8* __restrict__ QKs,
                      u16* __restrict__ O) {
    size_t e = ((size_t)blockIdx.x * 256 + threadIdx.x) * 4;    // 24576 blocks
    uchar4 v = *(const uchar4*)(V + e);
    size_t d = e % D_;
    size_t b = (e / ((size_t)S_ * D_)) % B_;
    size_t t = e / BSD_;
    uchar4 qk = *(const uchar4*)(QKs + t * (B_ * D_) + b * D_ + d);
    ushort4 o;
    o.x = (v.x & qk.x) ? 0x3F80 : 0;
    o.y = (v.y & qk.y) ? 0x3F80 : 0;
    o.z = (v.z & qk.z) ? 0x3F80 : 0;
    o.w = (v.w & qk.w) ? 0x3F80 : 0;
    *(ushort4*)(O + e) = o;
}

// ---- block reduction helper (final LN only; tolerance is loose here) ----
__device__ __forceinline__ float block_sum(float v, float* red) {
    #pragma unroll
    for (int o = 32; o > 0; o >>= 1) v += __shfl_down(v, o, 64);
    int lane = threadIdx.x & 63, w = threadIdx.x >> 6;
    __syncthreads();
    if (lane == 0) red[w] = v;
    __syncthreads();
    return (red[0] + red[1]) + (red[2] + red[3]);
}

__global__ __launch_bounds__(256)
void k_lnfinal(const float* __restrict__ Y, const float* __restrict__ g,
               const float* __restrict__ bt, float* __restrict__ out) {
    #pragma clang fp contract(off)
    __shared__ float red[4];
    size_t row = (size_t)blockIdx.x * D_;       // 32768 rows
    int tid = threadIdx.x;
    float y[3];
    float s = 0.f;
    #pragma unroll
    for (int j = 0; j < 3; ++j) { y[j] = Y[row + tid + j * 256]; s += y[j]; }
    float mean = block_sum(s, red) / 768.0f;
    float q = 0.f;
    #pragma unroll
    for (int j = 0; j < 3; ++j) { float d = y[j] - mean; q += d * d; }
    float var = block_sum(q, red) / 768.0f;
    float inv = 1.0f / __fsqrt_rn(var + LN_EPS);
    #pragma unroll
    for (int j = 0; j < 3; ++j) {
        int c = tid + j * 256;
        out[row + c] = (y[j] - mean) * inv * g[c] + bt[c];
    }
}

extern "C" void kernel_launch(void* const* d_in, const int* in_sizes, int n_in,
                              void* d_out, int out_size, void* d_ws, size_t ws_size,
                              hipStream_t stream) {
    const float* x  = (const float*)d_in[0];
    const float* wq = (const float*)d_in[1];
    const float* wk = (const float*)d_in[2];
    const float* wv = (const float*)d_in[3];
    const float* wo = (const float*)d_in[4];
    const float* gq = (const float*)d_in[5];
    const float* bq = (const float*)d_in[6];
    const float* gk = (const float*)d_in[7];
    const float* bk = (const float*)d_in[8];
    const float* gv = (const float*)d_in[9];
    const float* bv = (const float*)d_in[10];
    const float* go = (const float*)d_in[11];
    const float* bo = (const float*)d_in[12];
    float* out = (float*)d_out;

    char* ws = (char*)d_ws;
    size_t off = 0;
    auto alloc = [&](size_t bytes) -> void* {
        void* p = ws + off;
        off += (bytes + 255) & ~(size_t)255;
        return p;
    };
    u64* Am    = (u64*)alloc((size_t)T_ * 12 * BS_ * 8);     // 3 MB bitmasks
    float* Y   = (float*)alloc((size_t)M_ * D_ * 4);         // 96 MB GEMM out
    u8* Qs     = (u8*)alloc((size_t)M_ * D_);
    u8* Ks     = (u8*)alloc((size_t)M_ * D_);
    u8* Vs     = (u8*)alloc((size_t)M_ * D_);
    u16* QKVb  = (u16*)alloc((size_t)M_ * D_ * 2);           // 48 MB bf16
    u16* Wo    = (u16*)alloc((size_t)D_ * D_ * 2);
    float* QK  = (float*)alloc((size_t)T_ * B_ * D_ * 4);
    u8* QKs    = (u8*)alloc((size_t)T_ * B_ * D_);

    // 1. IF over x -> bitmasks (bit-exact)
    k_if_mask<<<BS_, 768, 0, stream>>>(x, Am);
    // 2. wo -> bf16 transposed
    k_wconv_o<<<(D_ * D_) / 256, 256, 0, stream>>>(wo, Wo);
    // 3. Q/K/V: bitwise-np GEMM + f64-LN + IF
    k_bitgemm<<<M_ / 16, 192, 0, stream>>>(Am, wq, Y);
    k_lnif<<<BS_ / 4, 256, 0, stream>>>(Y, gq, bq, Qs);
    k_bitgemm<<<M_ / 16, 192, 0, stream>>>(Am, wk, Y);
    k_lnif<<<BS_ / 4, 256, 0, stream>>>(Y, gk, bk, Ks);
    k_bitgemm<<<M_ / 16, 192, 0, stream>>>(Am, wv, Y);
    k_lnif<<<BS_ / 4, 256, 0, stream>>>(Y, gv, bv, Vs);
    // 4. QK column-dot + IF (integer-exact)
    hipMemsetAsync(QK, 0, (size_t)T_ * B_ * D_ * 4, stream);
    k_qkred<<<T_ * B_ * 8, 192, 0, stream>>>(Qs, Ks, QK);
    k_qkif<<<(B_ * D_) / 256, 256, 0, stream>>>(QK, QKs);
    // 5. QKV = V * QKs -> bf16
    k_qkv<<<(M_ * D_) / 4 / 256, 256, 0, stream>>>(Vs, QKs, QKVb);
    // 6. output projection (bf16 MFMA; loose tolerance) + final LN
    k_gemm<<<(M_ / 128) * (D_ / 128), 256, 0, stream>>>(QKVb, Wo, Y, D_ / 128, D_);
    k_lnfinal<<<M_, 256, 0, stream>>>(Y, go, bo, out);
}